// Round 5
// baseline (44.314 us; speedup 1.0000x reference)
//
#include <hip/hip_runtime.h>
#include <cstddef>

#define IOU_POS_T 0.6f
#define IOU_NEG_T 0.45f
#define F_EPS 1e-6f
#define F_ALPHA 0.25f
#define F_BETA (1.0f/9.0f)
#define MAXM 64
#define BPC 4                 // batches per grid.y chunk
#define TBLMAX (BPC*MAXM)
#define BINF 3.402823466e+38f

__device__ __forceinline__ void fp_barrier(float& x) { asm volatile("" : "+v"(x)); }

// ---------------- Pass A: masks + per-GT argmax (batch-looped) -----------------
__global__ void __launch_bounds__(256)
dl_assign(const float* __restrict__ anchors, const float* __restrict__ gt_boxes,
          unsigned long long* __restrict__ masks, unsigned long long* __restrict__ cells,
          int N, int M, int B, int nblkx)
{
    const int blk = blockIdx.x, chunk = blockIdx.y, tid = threadIdx.x;
    const int i = blk * 256 + tid;
    const int nb = min(BPC, B - chunk * BPC);      // batches in this chunk
    const int TBL = nb * M;
    const int gtbase = chunk * BPC * M;            // flat (b,m) base
    __shared__ float gmnx[TBLMAX], gmny[TBLMAX], gmxx[TBLMAX], gmxy[TBLMAX], gar[TBLMAX];
    __shared__ unsigned long long lcell[TBLMAX];
    __shared__ unsigned long long maskv[BPC];
    __shared__ float wbb[4][4];

    for (int k = tid; k < TBL; k += 256) {
        const float* g = gt_boxes + (size_t)(gtbase + k) * 5;
        float cx = g[0], cy = g[1], w = g[2], l = g[3];
        float hw = w * 0.5f, hl = l * 0.5f;
        gmnx[k] = cx - hw; gmny[k] = cy - hl;
        gmxx[k] = cx + hw; gmxy[k] = cy + hl;
        gar[k]  = w * l;
        lcell[k] = 0ull;
    }
    const bool act = i < N;
    float amnx = BINF, amny = BINF, amxx = -BINF, amxy = -BINF, area_a = 0.0f;
    if (act) {
        const float* a = anchors + (size_t)i * 5;
        float ax = a[0], ay = a[1], aw = a[2], al = a[3];
        amnx = ax - aw * 0.5f; amny = ay - al * 0.5f;
        amxx = ax + aw * 0.5f; amxy = ay + al * 0.5f;
        area_a = aw * al; fp_barrier(area_a);
    }
    float r0 = amnx, r1 = amny, r2 = amxx, r3 = amxy;
    #pragma unroll
    for (int off = 32; off; off >>= 1) {
        r0 = fminf(r0, __shfl_xor(r0, off));
        r1 = fminf(r1, __shfl_xor(r1, off));
        r2 = fmaxf(r2, __shfl_xor(r2, off));
        r3 = fmaxf(r3, __shfl_xor(r3, off));
    }
    const int wave = tid >> 6;
    if ((tid & 63) == 0) { wbb[wave][0] = r0; wbb[wave][1] = r1; wbb[wave][2] = r2; wbb[wave][3] = r3; }
    __syncthreads();
    if (tid < 64) {    // wave 0: all ballots upfront
        float bmnx = fminf(fminf(wbb[0][0], wbb[1][0]), fminf(wbb[2][0], wbb[3][0]));
        float bmny = fminf(fminf(wbb[0][1], wbb[1][1]), fminf(wbb[2][1], wbb[3][1]));
        float bmxx = fmaxf(fmaxf(wbb[0][2], wbb[1][2]), fmaxf(wbb[2][2], wbb[3][2]));
        float bmxy = fmaxf(fmaxf(wbb[0][3], wbb[1][3]), fmaxf(wbb[2][3], wbb[3][3]));
        for (int j = 0; j < nb; ++j) {
            bool ov = false;
            if (tid < M) {
                const int k = j * M + tid;
                float wxb = fminf(bmxx, gmxx[k]) - fmaxf(bmnx, gmnx[k]);
                float wyb = fminf(bmxy, gmxy[k]) - fmaxf(bmny, gmny[k]);
                ov = (wxb > 0.0f) && (wyb > 0.0f);
            }
            unsigned long long bal = __ballot(ov);
            if (tid == 0) {
                maskv[j] = bal;
                masks[(size_t)(chunk * BPC + j) * nblkx + blk] = bal;
            }
        }
    }
    __syncthreads();
    if (act) {
        for (int j = 0; j < nb; ++j) {
            unsigned long long mask = maskv[j];
            const int off = j * M;
            while (mask) {
                const int m = (int)__builtin_ctzll(mask); mask &= mask - 1;
                const int k = off + m;
                float wx = fminf(amxx, gmxx[k]) - fmaxf(amnx, gmnx[k]); wx = fmaxf(wx, 0.0f);
                float wy = fminf(amxy, gmxy[k]) - fmaxf(amny, gmny[k]); wy = fmaxf(wy, 0.0f);
                float inter = wx * wy; fp_barrier(inter);
                if (inter > 0.0f) {
                    float denom = (area_a + gar[k]) - inter + F_EPS;
                    float iou = inter / denom;
                    // higher iou wins; equal iou -> LOWER anchor index (numpy first-occurrence)
                    unsigned long long key =
                        ((unsigned long long)__float_as_uint(iou) << 32) | (unsigned)(~(unsigned)i);
                    atomicMax(&lcell[k], key);
                }
            }
        }
    }
    __syncthreads();
    for (int k = tid; k < TBL; k += 256) {
        unsigned long long v = lcell[k];
        if (v) atomicMax(cells + gtbase + k, v);
    }
}

// ---------------- Pass B: losses (batch-looped, sync-free inner loop) ----------
__global__ void __launch_bounds__(256)
dl_loss(const float* __restrict__ cls_logits, const float* __restrict__ box_preds,
        const float* __restrict__ intent_logits, const float* __restrict__ anchors,
        const float* __restrict__ gt_boxes, const int* __restrict__ gt_ints,
        const unsigned long long* __restrict__ cells,
        const unsigned long long* __restrict__ masks,
        float4* __restrict__ parts, int N, int M, int B, int C, int nblkx)
{
    const int blk = blockIdx.x, chunk = blockIdx.y, tid = threadIdx.x;
    const int ibase = blk * 256;
    const int i = ibase + tid;
    const int nb = min(BPC, B - chunk * BPC);
    const int TBL = nb * M;
    const int gtbase = chunk * BPC * M;
    const bool act = i < N;

    unsigned long long msk[BPC];
    float xv[BPC];
    unsigned long long any = 0ull;
    for (int j = 0; j < BPC; ++j) {
        msk[j] = (j < nb) ? masks[(size_t)(chunk * BPC + j) * nblkx + blk] : 0ull;
        any |= msk[j];
        xv[j] = (j < nb && act) ? cls_logits[(size_t)(chunk * BPC + j) * N + i] : 0.0f;
    }

    __shared__ float gmnx[TBLMAX], gmny[TBLMAX], gmxx[TBLMAX], gmxy[TBLMAX], gar[TBLMAX];
    __shared__ float gcx[TBLMAX], gcy[TBLMAX], gw[TBLMAX], gl[TBLMAX], ga[TBLMAX];
    __shared__ int gint[TBLMAX];
    __shared__ unsigned int sforce[256];

    float ax = 0, ay = 0, aw = 0, al = 0, aa = 0;
    float amnx = 0, amny = 0, amxx = 0, amxy = 0, area_a = 0.0f;
    if (any) {
        sforce[tid] = 0;
        for (int k = tid; k < TBL; k += 256) {
            const float* g = gt_boxes + (size_t)(gtbase + k) * 5;
            float cx = g[0], cy = g[1], w = g[2], l = g[3], ang = g[4];
            float hw = w * 0.5f, hl = l * 0.5f;
            gmnx[k] = cx - hw; gmny[k] = cy - hl;
            gmxx[k] = cx + hw; gmxy[k] = cy + hl;
            gar[k]  = w * l;
            gcx[k] = cx; gcy[k] = cy; gw[k] = w; gl[k] = l; ga[k] = ang;
            gint[k] = gt_ints[gtbase + k];
        }
        if (act) {
            const float* a = anchors + (size_t)i * 5;
            ax = a[0]; ay = a[1]; aw = a[2]; al = a[3]; aa = a[4];
            amnx = ax - aw * 0.5f; amny = ay - al * 0.5f;
            amxx = ax + aw * 0.5f; amxy = ay + al * 0.5f;
            area_a = aw * al; fp_barrier(area_a);
        }
    }
    __syncthreads();
    if (any) {       // forced-anchor map: bit j of sforce[t] = forced in batch j
        for (int k = tid; k < TBL; k += 256) {
            unsigned long long cell = cells[gtbase + k];
            if (cell) {
                float fiou = __uint_as_float((unsigned)(cell >> 32));
                int fi = (int)(~(unsigned)cell);
                if (fiou >= IOU_NEG_T && fi >= ibase && fi < ibase + 256)
                    atomicOr(&sforce[fi - ibase], 1u << (k / M));
            }
        }
    }
    __syncthreads();

    float cls_acc = 0.0f, box_acc = 0.0f, int_acc = 0.0f, np_acc = 0.0f;
    if (act) {
        const unsigned int myforce = any ? sforce[tid] : 0u;
        for (int j = 0; j < nb; ++j) {
            const float x = xv[j];
            unsigned long long sm = msk[j];
            if (!sm) {   // pure-negative (blk,b): lean focal, t=0
                float ce = fmaxf(x, 0.0f) + log1pf(expf(-fabsf(x)));
                float p = 1.0f / (1.0f + expf(-x));
                cls_acc += (1.0f - F_ALPHA) * ce * (p * p);
                continue;
            }
            const int off = j * M;
            float bestv = 0.0f; int bestm = 0;
            while (sm) {
                const int m = (int)__builtin_ctzll(sm); sm &= sm - 1;
                const int k = off + m;
                float wx = fminf(amxx, gmxx[k]) - fmaxf(amnx, gmnx[k]); wx = fmaxf(wx, 0.0f);
                float wy = fminf(amxy, gmxy[k]) - fmaxf(amny, gmny[k]); wy = fmaxf(wy, 0.0f);
                float inter = wx * wy; fp_barrier(inter);
                if (inter > 0.0f) {
                    float denom = (area_a + gar[k]) - inter + F_EPS;
                    float iou = inter / denom;
                    if (iou > bestv) { bestv = iou; bestm = m; }   // strict > keeps first index
                }
            }
            const bool forced = (myforce >> j) & 1u;
            const bool pos = (bestv >= IOU_POS_T) || forced;
            const bool neg = bestv < IOU_NEG_T;
            if (pos || neg) {
                float t = pos ? 1.0f : 0.0f;
                float ce = fmaxf(x, 0.0f) - x * t + log1pf(expf(-fabsf(x)));
                float p = 1.0f / (1.0f + expf(-x));
                float p_t = p * t + (1.0f - p) * (1.0f - t);
                float a_t = F_ALPHA * t + (1.0f - F_ALPHA) * (1.0f - t);
                float om = 1.0f - p_t;
                cls_acc += a_t * ce * (om * om);
            }
            if (pos) {
                np_acc += 1.0f;
                const int k = off + bestm;
                const int b = chunk * BPC + j;
                float dx = (gcx[k] - ax) / (aw + F_EPS);
                float dy = (gcy[k] - ay) / (al + F_EPS);
                float dwv = logf(gw[k] / (aw + F_EPS) + F_EPS);
                float dlv = logf(gl[k] / (al + F_EPS) + F_EPS);
                float da = ga[k] - aa;
                float tgt6[6] = { dx, dy, dwv, dlv, sinf(da), cosf(da) };
                const float* bp = box_preds + ((size_t)b * N + i) * 6;
                #pragma unroll
                for (int q = 0; q < 6; ++q) {
                    float d = fabsf(bp[q] - tgt6[q]);
                    box_acc += (d < F_BETA) ? (0.5f * d * d / F_BETA) : (d - 0.5f * F_BETA);
                }
                const float* il = intent_logits + ((size_t)b * N + i) * C;
                float mx = il[0];
                for (int c = 1; c < C; ++c) mx = fmaxf(mx, il[c]);
                float se = 0.0f;
                for (int c = 0; c < C; ++c) se += expf(il[c] - mx);
                int tg = gint[k]; tg = tg < 0 ? 0 : (tg > C - 1 ? C - 1 : tg);
                int_acc += (mx + logf(se)) - il[tg];
            }
        }
    }

    #pragma unroll
    for (int off = 32; off; off >>= 1) {
        cls_acc += __shfl_down(cls_acc, off);
        box_acc += __shfl_down(box_acc, off);
        int_acc += __shfl_down(int_acc, off);
        np_acc  += __shfl_down(np_acc, off);
    }
    __shared__ float q0[4], q1[4], q2[4], q3[4];
    const int wave = tid >> 6;
    if ((tid & 63) == 0) { q0[wave] = cls_acc; q1[wave] = box_acc; q2[wave] = int_acc; q3[wave] = np_acc; }
    __syncthreads();
    if (tid == 0) {
        parts[(size_t)chunk * nblkx + blk] =
            make_float4(q0[0] + q0[1] + q0[2] + q0[3],
                        q1[0] + q1[1] + q1[2] + q1[3],
                        q2[0] + q2[1] + q2[2] + q2[3],
                        q3[0] + q3[1] + q3[2] + q3[3]);
    }
}

// ---------------- reduce + finalize --------------------------------------------
__global__ void __launch_bounds__(256)
dl_reduce(const float4* __restrict__ parts, int total, float* __restrict__ out)
{
    const int tid = threadIdx.x;
    float c = 0, bx = 0, it = 0, np = 0;
    for (int k = tid; k < total; k += 256) {
        float4 v = parts[k];
        c += v.x; bx += v.y; it += v.z; np += v.w;
    }
    #pragma unroll
    for (int off = 32; off; off >>= 1) {
        c  += __shfl_down(c, off);
        bx += __shfl_down(bx, off);
        it += __shfl_down(it, off);
        np += __shfl_down(np, off);
    }
    __shared__ float q0[4], q1[4], q2[4], q3[4];
    const int wave = tid >> 6;
    if ((tid & 63) == 0) { q0[wave] = c; q1[wave] = bx; q2[wave] = it; q3[wave] = np; }
    __syncthreads();
    if (tid == 0) {
        float cs = q0[0] + q0[1] + q0[2] + q0[3];
        float bs = q1[0] + q1[1] + q1[2] + q1[3];
        float is = q2[0] + q2[1] + q2[2] + q2[3];
        float ns = q3[0] + q3[1] + q3[2] + q3[3];
        float denom = fmaxf(1.0f, ns);
        float cls = cs / denom, bo = bs / denom, in_ = is / denom;
        out[0] = cls + bo + 0.5f * in_;
        out[1] = cls;
        out[2] = bo;
        out[3] = in_;
        out[4] = ns;
    }
}

extern "C" void kernel_launch(void* const* d_in, const int* in_sizes, int n_in,
                              void* d_out, int out_size, void* d_ws, size_t ws_size,
                              hipStream_t stream) {
    const float* cls_logits    = (const float*)d_in[0];
    const float* box_preds     = (const float*)d_in[1];
    const float* intent_logits = (const float*)d_in[2];
    const float* anchors       = (const float*)d_in[3];
    const float* gt_boxes      = (const float*)d_in[4];
    const int*   gt_ints       = (const int*)d_in[5];

    const int N = in_sizes[3] / 5;              // anchors [N,5]
    const int B = in_sizes[0] / N;              // cls_logits [B,N,1]
    const int M = in_sizes[5] / B;              // gt_intentions [B,M]
    const int C = in_sizes[2] / in_sizes[0];    // intention_logits [B,N,C]
    const int nblkx = (N + 255) / 256;
    const int nchunk = (B + BPC - 1) / BPC;

    char* ws = (char*)d_ws;
    unsigned long long* cells = (unsigned long long*)ws;            // B*M*8
    size_t off = ((size_t)B * M * 8 + 255) & ~(size_t)255;
    unsigned long long* masks = (unsigned long long*)(ws + off);    // B*nblkx*8
    off = (off + (size_t)B * nblkx * 8 + 255) & ~(size_t)255;
    float4* parts = (float4*)(ws + off);                            // nchunk*nblkx*16

    hipMemsetAsync(cells, 0, (size_t)B * M * 8, stream);

    dim3 grid(nblkx, nchunk);
    dl_assign<<<grid, 256, 0, stream>>>(anchors, gt_boxes, masks, cells, N, M, B, nblkx);
    dl_loss<<<grid, 256, 0, stream>>>(cls_logits, box_preds, intent_logits, anchors,
                                      gt_boxes, gt_ints, cells, masks, parts, N, M, B, C, nblkx);
    dl_reduce<<<1, 256, 0, stream>>>(parts, nblkx * nchunk, (float*)d_out);
}